// Round 17
// baseline (87.213 us; speedup 1.0000x reference)
//
#include <hip/hip_runtime.h>
#include <hip/hip_bf16.h>
#include <stdint.h>

#define NNODES 10000
#define NEDGES 320000
#define DIM    256
#define KTOT   512
#define LN_EPS 1e-5f
#define BCAP   96     // per-node bucket capacity (max degree; P(exceed) ~ 1e-20)

typedef __attribute__((ext_vector_type(4))) float f32x4;
typedef __attribute__((ext_vector_type(8))) short bf16x8;

__device__ __forceinline__ ushort f2bf(float f) {
    union { float f; uint32_t u; } v; v.f = f;
    uint32_t r = v.u + 0x7fffu + ((v.u >> 16) & 1u);   // RNE
    return (ushort)(r >> 16);
}
__device__ __forceinline__ float bf2f(ushort u) {
    union { float f; uint32_t u; } v; v.u = ((uint32_t)u) << 16;
    return v.f;
}

// ---- K1: scatter (blocks [0,320), dispatched first) ∥ prep (blocks [320,3844)) ----
// Scatter: 4 grid-strided edges/thread -> 4 independent atomic round-trips in
// flight; srow ushort. cnt pre-zeroed by hipMemsetAsync.
// Prep: cast x->bf16; fragment-arrange W_msg (Wcat) and W_upd (Wua).
__global__ __launch_bounds__(256)
void prep_scatter(const float* __restrict__ x, const float* __restrict__ Wm,
                  const float* __restrict__ Wu, ushort* __restrict__ xb,
                  ushort* __restrict__ Wcat, ushort* __restrict__ Wua,
                  const int* __restrict__ eidx, int* __restrict__ cnt,
                  ushort* __restrict__ srow) {
    if (blockIdx.x < 320) {
        const int t = blockIdx.x * 256 + threadIdx.x;  // 0..81919
        int d[4], r[4];
#pragma unroll
        for (int j = 0; j < 3; ++j) {                  // e < 245760 always valid
            int e = t + j * 81920;
            d[j] = eidx[NEDGES + e];
            r[j] = eidx[e];
        }
        const bool ok3 = t < (NEDGES - 3 * 81920);     // 74240
        if (ok3) { d[3] = eidx[NEDGES + t + 245760]; r[3] = eidx[t + 245760]; }
        int p[4];
#pragma unroll
        for (int j = 0; j < 3; ++j) p[j] = atomicAdd(&cnt[d[j]], 1);
        if (ok3) p[3] = atomicAdd(&cnt[d[3]], 1);
#pragma unroll
        for (int j = 0; j < 3; ++j)
            if (p[j] < BCAP) srow[d[j] * BCAP + p[j]] = (ushort)r[j];
        if (ok3 && p[3] < BCAP) srow[d[3] * BCAP + p[3]] = (ushort)r[3];
        return;
    }
    int tid = (blockIdx.x - 320) * 256 + threadIdx.x;  // 3524*256 = 902144
    if (tid < 640000) {                                // x cast, one float4 each
        float4 v = reinterpret_cast<const float4*>(x)[tid];
        ushort4 o;
        o.x = f2bf(v.x); o.y = f2bf(v.y); o.z = f2bf(v.z); o.w = f2bf(v.w);
        reinterpret_cast<ushort4*>(xb)[tid] = o;
    } else {
        int t = tid - 640000;                          // < 262144
        if (t < 131072) {
            int kk  = t >> 14;
            int rem = t & 16383;
            int g   = rem >> 9;
            int kg  = (rem >> 7) & 3;
            int ml  = (rem >> 3) & 15;
            int j   = rem & 7;
            int k = kk * 32 + kg * 8 + j;
            int n = g * 16 + ml;
            float v = (n < 256) ? Wm[k * DIM + n] : Wm[(k + 256) * DIM + (n - 256)];
            Wcat[t] = f2bf(v);
        } else {
            int rem = t - 131072;
            int kk  = rem >> 13;
            int nt  = (rem >> 9) & 15;
            int kg  = (rem >> 7) & 3;
            int ml  = (rem >> 3) & 15;
            int j   = rem & 7;
            int k = kk * 32 + kg * 8 + j;
            int n = nt * 16 + ml;
            Wua[rem] = f2bf(Wu[k * DIM + n]);
        }
    }
}

// ---- K2: U|V GEMM. U = x @ W_msg[:256] (bf16), V = x @ W_msg[256:] + b (fp32)
// 625 blocks x 256 thr; block = 16 nodes x 512 cols; wave wq owns 128 cols.
__global__ __launch_bounds__(256)
void uv_gemm(const ushort* __restrict__ xb, const ushort* __restrict__ Wcat,
             const float* __restrict__ bmsg, ushort* __restrict__ Ub,
             float* __restrict__ Vf) {
    const int wq   = threadIdx.x >> 6;
    const int lane = threadIdx.x & 63;
    const int ml = lane & 15, kg = lane >> 4;
    const int nb = blockIdx.x * 16;
    const uint arow = (uint)(nb + ml) * DIM;

    f32x4 acc[8];
#pragma unroll
    for (int nt = 0; nt < 8; ++nt) acc[nt] = (f32x4){0.f, 0.f, 0.f, 0.f};

#pragma unroll
    for (int kk = 0; kk < 8; ++kk) {
        bf16x8 a = *reinterpret_cast<const bf16x8*>(xb + arow + kk * 32 + kg * 8);
#pragma unroll
        for (int nt = 0; nt < 8; ++nt) {
            bf16x8 b = *reinterpret_cast<const bf16x8*>(Wcat + kk * 16384 + (wq * 8 + nt) * 512 + lane * 8);
            acc[nt] = __builtin_amdgcn_mfma_f32_16x16x32_bf16(a, b, acc[nt], 0, 0, 0);
        }
    }

    if (wq < 2) {                                   // U half: bf16
#pragma unroll
        for (int nt = 0; nt < 8; ++nt) {
            const int col = wq * 128 + nt * 16 + ml;
#pragma unroll
            for (int i = 0; i < 4; ++i)
                Ub[(size_t)(nb + kg * 4 + i) * 256 + col] = f2bf(acc[nt][i]);
        }
    } else {                                        // V half: fp32, bias folded
#pragma unroll
        for (int nt = 0; nt < 8; ++nt) {
            const int col = (wq - 2) * 128 + nt * 16 + ml;
            const float bb = bmsg[col];
#pragma unroll
            for (int i = 0; i < 4; ++i)
                Vf[(size_t)(nb + kg * 4 + i) * 256 + col] = acc[nt][i] + bb;
        }
    }
}

// ---- K3: edge combine (standalone): aggb[d] = bf16( sum relu(U[src] + V[d]) )
// 1250 blocks x 256 thr (4 waves); wave reduces 2 nodes; lane owns 8 cols
// (16B loads); 32-lane halves split edges by parity, 4-deep ILP, one
// shfl_xor(32) combine, bf16x8 store.
__global__ __launch_bounds__(256)
void edge_combine(const ushort* __restrict__ Ub, const float* __restrict__ Vf,
                  const ushort* __restrict__ srow, const int* __restrict__ cnt,
                  ushort* __restrict__ aggb) {
    const int wave = threadIdx.x >> 6, lane = threadIdx.x & 63;
    const int nb = blockIdx.x * 8;
    const int el = lane >> 5;           // half id (edge-parity)
    const int cl = lane & 31;
    const int c0 = cl * 8;              // 8 cols owned

#pragma unroll
    for (int nn = 0; nn < 2; ++nn) {
        const int d = nb + wave * 2 + nn;
        int deg = cnt[d]; deg = deg < BCAP ? deg : BCAP;
        const int beg = d * BCAP;
        const float4 va = *reinterpret_cast<const float4*>(&Vf[(size_t)d * 256 + c0]);
        const float4 vb = *reinterpret_cast<const float4*>(&Vf[(size_t)d * 256 + c0 + 4]);
        float s[8];
#pragma unroll
        for (int j = 0; j < 8; ++j) s[j] = 0.f;

#define ACC8(U) do { \
        s[0] += fmaxf(bf2f((ushort)(U)[0]) + va.x, 0.f); \
        s[1] += fmaxf(bf2f((ushort)(U)[1]) + va.y, 0.f); \
        s[2] += fmaxf(bf2f((ushort)(U)[2]) + va.z, 0.f); \
        s[3] += fmaxf(bf2f((ushort)(U)[3]) + va.w, 0.f); \
        s[4] += fmaxf(bf2f((ushort)(U)[4]) + vb.x, 0.f); \
        s[5] += fmaxf(bf2f((ushort)(U)[5]) + vb.y, 0.f); \
        s[6] += fmaxf(bf2f((ushort)(U)[6]) + vb.z, 0.f); \
        s[7] += fmaxf(bf2f((ushort)(U)[7]) + vb.w, 0.f); } while (0)

        int i = el;
        for (; i + 6 < deg; i += 8) {    // 4 rows in flight per half
            int r0 = srow[beg + i],     r1 = srow[beg + i + 2];
            int r2 = srow[beg + i + 4], r3 = srow[beg + i + 6];
            bf16x8 u0 = *reinterpret_cast<const bf16x8*>(&Ub[(size_t)r0 * 256 + c0]);
            bf16x8 u1 = *reinterpret_cast<const bf16x8*>(&Ub[(size_t)r1 * 256 + c0]);
            bf16x8 u2 = *reinterpret_cast<const bf16x8*>(&Ub[(size_t)r2 * 256 + c0]);
            bf16x8 u3 = *reinterpret_cast<const bf16x8*>(&Ub[(size_t)r3 * 256 + c0]);
            ACC8(u0); ACC8(u1); ACC8(u2); ACC8(u3);
        }
        for (; i < deg; i += 2) {
            int r = srow[beg + i];
            bf16x8 u = *reinterpret_cast<const bf16x8*>(&Ub[(size_t)r * 256 + c0]);
            ACC8(u);
        }
#undef ACC8
#pragma unroll
        for (int j = 0; j < 8; ++j) s[j] += __shfl_xor(s[j], 32);
        if (el == 0) {
            union { bf16x8 v; ushort h[8]; } o;
#pragma unroll
            for (int j = 0; j < 8; ++j) o.h[j] = f2bf(s[j]);
            *reinterpret_cast<bf16x8*>(&aggb[(size_t)d * 256 + c0]) = o.v;
        }
    }
}

// ---- K4: node update GEMM + bias + relu + LayerNorm (64-node tiles) ----
// 157 blocks x 512 thr (8 waves = 2 wr x 4 wc): wave = 32 nodes x 64 cols.
__global__ __launch_bounds__(512)
void node_ln(const ushort* __restrict__ xb, const ushort* __restrict__ aggb,
             const ushort* __restrict__ Wua, const float* __restrict__ bupd,
             const float* __restrict__ gamma, const float* __restrict__ beta,
             float* __restrict__ out) {
    __shared__ float pS[64][4][2];      // [node_local][wc][sum,ssq]

    const int wave = threadIdx.x >> 6;
    const int lane = threadIdx.x & 63;
    const int ml = lane & 15, kg = lane >> 4;
    const int wr = wave >> 2, wc = wave & 3;
    const int nb = blockIdx.x * 64;

    uint arow[2];
#pragma unroll
    for (int t = 0; t < 2; ++t) {
        int n = nb + wr * 32 + t * 16 + ml;
        arow[t] = (uint)(n < NNODES ? n : NNODES - 1) * DIM;
    }

    f32x4 acc[2][4];
#pragma unroll
    for (int t = 0; t < 2; ++t)
#pragma unroll
        for (int nt = 0; nt < 4; ++nt) acc[t][nt] = (f32x4){0.f, 0.f, 0.f, 0.f};

#pragma unroll
    for (int kk = 0; kk < 8; ++kk) {                  // k in [0,256): A = xb
        bf16x8 a0 = *reinterpret_cast<const bf16x8*>(xb + arow[0] + kk * 32 + kg * 8);
        bf16x8 a1 = *reinterpret_cast<const bf16x8*>(xb + arow[1] + kk * 32 + kg * 8);
#pragma unroll
        for (int nt = 0; nt < 4; ++nt) {
            bf16x8 b = *reinterpret_cast<const bf16x8*>(Wua + kk * 8192 + (wc * 4 + nt) * 512 + lane * 8);
            acc[0][nt] = __builtin_amdgcn_mfma_f32_16x16x32_bf16(a0, b, acc[0][nt], 0, 0, 0);
            acc[1][nt] = __builtin_amdgcn_mfma_f32_16x16x32_bf16(a1, b, acc[1][nt], 0, 0, 0);
        }
    }
#pragma unroll
    for (int kk = 0; kk < 8; ++kk) {                  // k in [256,512): A = aggb
        bf16x8 a0 = *reinterpret_cast<const bf16x8*>(aggb + arow[0] + kk * 32 + kg * 8);
        bf16x8 a1 = *reinterpret_cast<const bf16x8*>(aggb + arow[1] + kk * 32 + kg * 8);
#pragma unroll
        for (int nt = 0; nt < 4; ++nt) {
            bf16x8 b = *reinterpret_cast<const bf16x8*>(Wua + 65536 + kk * 8192 + (wc * 4 + nt) * 512 + lane * 8);
            acc[0][nt] = __builtin_amdgcn_mfma_f32_16x16x32_bf16(a0, b, acc[0][nt], 0, 0, 0);
            acc[1][nt] = __builtin_amdgcn_mfma_f32_16x16x32_bf16(a1, b, acc[1][nt], 0, 0, 0);
        }
    }

    float sum[2][4], ssq[2][4];
#pragma unroll
    for (int t = 0; t < 2; ++t)
#pragma unroll
        for (int i = 0; i < 4; ++i) { sum[t][i] = 0.f; ssq[t][i] = 0.f; }
#pragma unroll
    for (int t = 0; t < 2; ++t)
#pragma unroll
        for (int nt = 0; nt < 4; ++nt) {
            const float bb = bupd[wc * 64 + nt * 16 + ml];
#pragma unroll
            for (int i = 0; i < 4; ++i) {
                float v = acc[t][nt][i] + bb;
                v = v > 0.f ? v : 0.f;
                acc[t][nt][i] = v;
                sum[t][i] += v;
                ssq[t][i] += v * v;
            }
        }
#pragma unroll
    for (int m = 1; m < 16; m <<= 1) {
#pragma unroll
        for (int t = 0; t < 2; ++t)
#pragma unroll
            for (int i = 0; i < 4; ++i) {
                sum[t][i] += __shfl_xor(sum[t][i], m);
                ssq[t][i] += __shfl_xor(ssq[t][i], m);
            }
    }
    if (ml == 0) {
#pragma unroll
        for (int t = 0; t < 2; ++t)
#pragma unroll
            for (int i = 0; i < 4; ++i) {
                int nl = wr * 32 + t * 16 + kg * 4 + i;
                pS[nl][wc][0] = sum[t][i];
                pS[nl][wc][1] = ssq[t][i];
            }
    }
    __syncthreads();

    float mu[2][4], rs[2][4];
#pragma unroll
    for (int t = 0; t < 2; ++t)
#pragma unroll
        for (int i = 0; i < 4; ++i) {
            int nl = wr * 32 + t * 16 + kg * 4 + i;
            float S = pS[nl][0][0] + pS[nl][1][0] + pS[nl][2][0] + pS[nl][3][0];
            float Q = pS[nl][0][1] + pS[nl][1][1] + pS[nl][2][1] + pS[nl][3][1];
            float m = S * (1.f / 256.f);
            float var = Q * (1.f / 256.f) - m * m;
            mu[t][i] = m;
            rs[t][i] = rsqrtf(var + LN_EPS);
        }
#pragma unroll
    for (int t = 0; t < 2; ++t)
#pragma unroll
        for (int nt = 0; nt < 4; ++nt) {
            const int cc = wc * 64 + nt * 16 + ml;
            const float g = gamma[cc], be = beta[cc];
#pragma unroll
            for (int i = 0; i < 4; ++i) {
                const int node = nb + wr * 32 + t * 16 + kg * 4 + i;
                if (node < NNODES)
                    out[(size_t)node * DIM + cc] = (acc[t][nt][i] - mu[t][i]) * rs[t][i] * g + be;
            }
        }
}

extern "C" void kernel_launch(void* const* d_in, const int* in_sizes, int n_in,
                              void* d_out, int out_size, void* d_ws, size_t ws_size,
                              hipStream_t stream) {
    const float* x    = (const float*)d_in[0];
    const int*   eidx = (const int*)  d_in[1];
    const float* Wm   = (const float*)d_in[2];
    const float* bm   = (const float*)d_in[3];
    const float* Wu   = (const float*)d_in[4];
    const float* bu   = (const float*)d_in[5];
    const float* gam  = (const float*)d_in[6];
    const float* bet  = (const float*)d_in[7];
    float* out = (float*)d_out;

    char* ws = (char*)d_ws;
    ushort* xb     = (ushort*)(ws);                    //  5,120,000 B
    ushort* Ub     = (ushort*)(ws +  5120000);         //  5,120,000 B
    float*  Vf     = (float*) (ws + 10240000);         // 10,240,000 B
    ushort* aggb   = (ushort*)(ws + 20480000);         //  5,120,000 B
    ushort* Wcat   = (ushort*)(ws + 25600000);         //    262,144 B
    ushort* Wua    = (ushort*)(ws + 25862144);         //    262,144 B
    int*    cnt    = (int*)   (ws + 26124288);         //     40,960 B
    ushort* srow   = (ushort*)(ws + 26165248);         //  1,920,000 B (end ~28.1 MB)

    hipMemsetAsync(cnt, 0, (size_t)NNODES * sizeof(int), stream);
    prep_scatter<<<3844, 256, 0, stream>>>(x, Wm, Wu, xb, Wcat, Wua, eidx, cnt, srow);
    uv_gemm<<<625, 256, 0, stream>>>(xb, Wcat, bm, Ub, Vf);
    edge_combine<<<1250, 256, 0, stream>>>(Ub, Vf, srow, cnt, aggb);
    node_ln<<<157, 512, 0, stream>>>(xb, aggb, Wua, bu, gam, bet, out);
}

// Round 18
// 83.405 us; speedup vs baseline: 1.0457x; 1.0457x over previous
//
#include <hip/hip_runtime.h>
#include <hip/hip_bf16.h>
#include <stdint.h>

#define NNODES 10000
#define NEDGES 320000
#define DIM    256
#define KTOT   512
#define LN_EPS 1e-5f
#define BCAP   96     // per-node bucket capacity (max degree; P(exceed) ~ 1e-20)

typedef __attribute__((ext_vector_type(4))) float f32x4;
typedef __attribute__((ext_vector_type(8))) short bf16x8;

__device__ __forceinline__ ushort f2bf(float f) {
    union { float f; uint32_t u; } v; v.f = f;
    uint32_t r = v.u + 0x7fffu + ((v.u >> 16) & 1u);   // RNE
    return (ushort)(r >> 16);
}
__device__ __forceinline__ float bf2f(ushort u) {
    union { float f; uint32_t u; } v; v.u = ((uint32_t)u) << 16;
    return v.f;
}

// ---- K1: prep — cast x->bf16, zero cnt, fragment-arrange both W matrices ----
__global__ __launch_bounds__(256)
void prep_all(const float* __restrict__ x, const float* __restrict__ Wm,
              const float* __restrict__ Wu, ushort* __restrict__ xb,
              ushort* __restrict__ Wcat, ushort* __restrict__ Wua,
              int4* __restrict__ cntz) {
    int tid = blockIdx.x * 256 + threadIdx.x;          // 3524*256 = 902144
    if (tid < 2560) cntz[tid] = (int4){0, 0, 0, 0};    // 10240 ints >= NNODES
    if (tid < 640000) {                                // x cast, one float4 each
        float4 v = reinterpret_cast<const float4*>(x)[tid];
        ushort4 o;
        o.x = f2bf(v.x); o.y = f2bf(v.y); o.z = f2bf(v.z); o.w = f2bf(v.w);
        reinterpret_cast<ushort4*>(xb)[tid] = o;
    } else {
        int t = tid - 640000;                          // < 262144
        if (t < 131072) {
            int kk  = t >> 14;
            int rem = t & 16383;
            int g   = rem >> 9;
            int kg  = (rem >> 7) & 3;
            int ml  = (rem >> 3) & 15;
            int j   = rem & 7;
            int k = kk * 32 + kg * 8 + j;
            int n = g * 16 + ml;
            float v = (n < 256) ? Wm[k * DIM + n] : Wm[(k + 256) * DIM + (n - 256)];
            Wcat[t] = f2bf(v);
        } else {
            int rem = t - 131072;
            int kk  = rem >> 13;
            int nt  = (rem >> 9) & 15;
            int kg  = (rem >> 7) & 3;
            int ml  = (rem >> 3) & 15;
            int j   = rem & 7;
            int k = kk * 32 + kg * 8 + j;
            int n = nt * 16 + ml;
            Wua[rem] = f2bf(Wu[k * DIM + n]);
        }
    }
}

// ---- K2: ILP bucket scatter (blocks [0,320)) ∥ U|V GEMM (blocks [320,945)) ----
__global__ __launch_bounds__(256)
void scatter_uv(const int* __restrict__ eidx, int* __restrict__ cnt,
                ushort* __restrict__ srow, const ushort* __restrict__ xb,
                const ushort* __restrict__ Wcat, const float* __restrict__ bmsg,
                ushort* __restrict__ Ub, float* __restrict__ Vf) {
    if (blockIdx.x < 320) {
        const int t = blockIdx.x * 256 + threadIdx.x;  // 0..81919
        int d[4], r[4];
#pragma unroll
        for (int j = 0; j < 3; ++j) {                  // e < 245760 always valid
            int e = t + j * 81920;
            d[j] = eidx[NEDGES + e];
            r[j] = eidx[e];
        }
        const bool ok3 = t < (NEDGES - 3 * 81920);     // 74240
        if (ok3) { d[3] = eidx[NEDGES + t + 245760]; r[3] = eidx[t + 245760]; }
        int p[4];
#pragma unroll
        for (int j = 0; j < 3; ++j) p[j] = atomicAdd(&cnt[d[j]], 1);
        if (ok3) p[3] = atomicAdd(&cnt[d[3]], 1);
#pragma unroll
        for (int j = 0; j < 3; ++j)
            if (p[j] < BCAP) srow[d[j] * BCAP + p[j]] = (ushort)r[j];
        if (ok3 && p[3] < BCAP) srow[d[3] * BCAP + p[3]] = (ushort)r[3];
        return;
    }
    // U = x @ W_msg[:256] (bf16), V = x @ W_msg[256:] + b (fp32).
    // 625 blocks x 256 thr; block = 16 nodes x 512 cols; wave wq owns 128 cols.
    const int wq   = threadIdx.x >> 6;
    const int lane = threadIdx.x & 63;
    const int ml = lane & 15, kg = lane >> 4;
    const int nb = (blockIdx.x - 320) * 16;
    const uint arow = (uint)(nb + ml) * DIM;

    f32x4 acc[8];
#pragma unroll
    for (int nt = 0; nt < 8; ++nt) acc[nt] = (f32x4){0.f, 0.f, 0.f, 0.f};

#pragma unroll
    for (int kk = 0; kk < 8; ++kk) {
        bf16x8 a = *reinterpret_cast<const bf16x8*>(xb + arow + kk * 32 + kg * 8);
#pragma unroll
        for (int nt = 0; nt < 8; ++nt) {
            bf16x8 b = *reinterpret_cast<const bf16x8*>(Wcat + kk * 16384 + (wq * 8 + nt) * 512 + lane * 8);
            acc[nt] = __builtin_amdgcn_mfma_f32_16x16x32_bf16(a, b, acc[nt], 0, 0, 0);
        }
    }

    if (wq < 2) {                                   // U half: bf16
#pragma unroll
        for (int nt = 0; nt < 8; ++nt) {
            const int col = wq * 128 + nt * 16 + ml;
#pragma unroll
            for (int i = 0; i < 4; ++i)
                Ub[(size_t)(nb + kg * 4 + i) * 256 + col] = f2bf(acc[nt][i]);
        }
    } else {                                        // V half: fp32, bias folded
#pragma unroll
        for (int nt = 0; nt < 8; ++nt) {
            const int col = (wq - 2) * 128 + nt * 16 + ml;
            const float bb = bmsg[col];
#pragma unroll
            for (int i = 0; i < 4; ++i)
                Vf[(size_t)(nb + kg * 4 + i) * 256 + col] = acc[nt][i] + bb;
        }
    }
}

// ---- K3: edge combine: aggb[d] = bf16( sum relu(U[src] + V[d]) ) ----
// 1250 blocks x 256 thr (4 waves); wave reduces 2 nodes, WHOLE-WAVE per edge:
// lane owns 4 cols (c0 = lane*4), so one edge = one wave-wide 512B row load;
// 8 wave-uniform edge indices arrive in ONE 16B load; 8-deep row-load ILP;
// no shuffles (each lane's 4-col partial is final); ushort4 store.
__global__ __launch_bounds__(256)
void edge_combine(const ushort* __restrict__ Ub, const float* __restrict__ Vf,
                  const ushort* __restrict__ srow, const int* __restrict__ cnt,
                  ushort* __restrict__ aggb) {
    const int wave = threadIdx.x >> 6, lane = threadIdx.x & 63;
    const int nb = blockIdx.x * 8;
    const int c0 = lane * 4;

#pragma unroll
    for (int nn = 0; nn < 2; ++nn) {
        const int d = nb + wave * 2 + nn;
        int deg = cnt[d]; deg = deg < BCAP ? deg : BCAP;
        const int beg = d * BCAP;                      // 96 | beg -> 16B-aligned i%8==0
        const float4 vc = *reinterpret_cast<const float4*>(&Vf[(size_t)d * 256 + c0]);
        float s0 = 0.f, s1 = 0.f, s2 = 0.f, s3 = 0.f;

        int i = 0;
        for (; i + 8 <= deg; i += 8) {
            union { int4 v; ushort h[8]; } idx;
            idx.v = *reinterpret_cast<const int4*>(&srow[beg + i]);  // 8 indices, 1 load
            ushort4 u[8];
#pragma unroll
            for (int j = 0; j < 8; ++j)
                u[j] = *reinterpret_cast<const ushort4*>(&Ub[(size_t)idx.h[j] * 256 + c0]);
#pragma unroll
            for (int j = 0; j < 8; ++j) {
                s0 += fmaxf(bf2f(u[j].x) + vc.x, 0.f);
                s1 += fmaxf(bf2f(u[j].y) + vc.y, 0.f);
                s2 += fmaxf(bf2f(u[j].z) + vc.z, 0.f);
                s3 += fmaxf(bf2f(u[j].w) + vc.w, 0.f);
            }
        }
        for (; i < deg; ++i) {
            int r = srow[beg + i];
            ushort4 u = *reinterpret_cast<const ushort4*>(&Ub[(size_t)r * 256 + c0]);
            s0 += fmaxf(bf2f(u.x) + vc.x, 0.f);
            s1 += fmaxf(bf2f(u.y) + vc.y, 0.f);
            s2 += fmaxf(bf2f(u.z) + vc.z, 0.f);
            s3 += fmaxf(bf2f(u.w) + vc.w, 0.f);
        }
        ushort4 o;
        o.x = f2bf(s0); o.y = f2bf(s1); o.z = f2bf(s2); o.w = f2bf(s3);
        *reinterpret_cast<ushort4*>(&aggb[(size_t)d * 256 + c0]) = o;
    }
}

// ---- K4: node update GEMM + bias + relu + LayerNorm (64-node tiles) ----
// 157 blocks x 512 thr (8 waves = 2 wr x 4 wc): wave = 32 nodes x 64 cols.
__global__ __launch_bounds__(512)
void node_ln(const ushort* __restrict__ xb, const ushort* __restrict__ aggb,
             const ushort* __restrict__ Wua, const float* __restrict__ bupd,
             const float* __restrict__ gamma, const float* __restrict__ beta,
             float* __restrict__ out) {
    __shared__ float pS[64][4][2];      // [node_local][wc][sum,ssq]

    const int wave = threadIdx.x >> 6;
    const int lane = threadIdx.x & 63;
    const int ml = lane & 15, kg = lane >> 4;
    const int wr = wave >> 2, wc = wave & 3;
    const int nb = blockIdx.x * 64;

    uint arow[2];
#pragma unroll
    for (int t = 0; t < 2; ++t) {
        int n = nb + wr * 32 + t * 16 + ml;
        arow[t] = (uint)(n < NNODES ? n : NNODES - 1) * DIM;
    }

    f32x4 acc[2][4];
#pragma unroll
    for (int t = 0; t < 2; ++t)
#pragma unroll
        for (int nt = 0; nt < 4; ++nt) acc[t][nt] = (f32x4){0.f, 0.f, 0.f, 0.f};

#pragma unroll
    for (int kk = 0; kk < 8; ++kk) {                  // k in [0,256): A = xb
        bf16x8 a0 = *reinterpret_cast<const bf16x8*>(xb + arow[0] + kk * 32 + kg * 8);
        bf16x8 a1 = *reinterpret_cast<const bf16x8*>(xb + arow[1] + kk * 32 + kg * 8);
#pragma unroll
        for (int nt = 0; nt < 4; ++nt) {
            bf16x8 b = *reinterpret_cast<const bf16x8*>(Wua + kk * 8192 + (wc * 4 + nt) * 512 + lane * 8);
            acc[0][nt] = __builtin_amdgcn_mfma_f32_16x16x32_bf16(a0, b, acc[0][nt], 0, 0, 0);
            acc[1][nt] = __builtin_amdgcn_mfma_f32_16x16x32_bf16(a1, b, acc[1][nt], 0, 0, 0);
        }
    }
#pragma unroll
    for (int kk = 0; kk < 8; ++kk) {                  // k in [256,512): A = aggb
        bf16x8 a0 = *reinterpret_cast<const bf16x8*>(aggb + arow[0] + kk * 32 + kg * 8);
        bf16x8 a1 = *reinterpret_cast<const bf16x8*>(aggb + arow[1] + kk * 32 + kg * 8);
#pragma unroll
        for (int nt = 0; nt < 4; ++nt) {
            bf16x8 b = *reinterpret_cast<const bf16x8*>(Wua + 65536 + kk * 8192 + (wc * 4 + nt) * 512 + lane * 8);
            acc[0][nt] = __builtin_amdgcn_mfma_f32_16x16x32_bf16(a0, b, acc[0][nt], 0, 0, 0);
            acc[1][nt] = __builtin_amdgcn_mfma_f32_16x16x32_bf16(a1, b, acc[1][nt], 0, 0, 0);
        }
    }

    float sum[2][4], ssq[2][4];
#pragma unroll
    for (int t = 0; t < 2; ++t)
#pragma unroll
        for (int i = 0; i < 4; ++i) { sum[t][i] = 0.f; ssq[t][i] = 0.f; }
#pragma unroll
    for (int t = 0; t < 2; ++t)
#pragma unroll
        for (int nt = 0; nt < 4; ++nt) {
            const float bb = bupd[wc * 64 + nt * 16 + ml];
#pragma unroll
            for (int i = 0; i < 4; ++i) {
                float v = acc[t][nt][i] + bb;
                v = v > 0.f ? v : 0.f;
                acc[t][nt][i] = v;
                sum[t][i] += v;
                ssq[t][i] += v * v;
            }
        }
#pragma unroll
    for (int m = 1; m < 16; m <<= 1) {
#pragma unroll
        for (int t = 0; t < 2; ++t)
#pragma unroll
            for (int i = 0; i < 4; ++i) {
                sum[t][i] += __shfl_xor(sum[t][i], m);
                ssq[t][i] += __shfl_xor(ssq[t][i], m);
            }
    }
    if (ml == 0) {
#pragma unroll
        for (int t = 0; t < 2; ++t)
#pragma unroll
            for (int i = 0; i < 4; ++i) {
                int nl = wr * 32 + t * 16 + kg * 4 + i;
                pS[nl][wc][0] = sum[t][i];
                pS[nl][wc][1] = ssq[t][i];
            }
    }
    __syncthreads();

    float mu[2][4], rs[2][4];
#pragma unroll
    for (int t = 0; t < 2; ++t)
#pragma unroll
        for (int i = 0; i < 4; ++i) {
            int nl = wr * 32 + t * 16 + kg * 4 + i;
            float S = pS[nl][0][0] + pS[nl][1][0] + pS[nl][2][0] + pS[nl][3][0];
            float Q = pS[nl][0][1] + pS[nl][1][1] + pS[nl][2][1] + pS[nl][3][1];
            float m = S * (1.f / 256.f);
            float var = Q * (1.f / 256.f) - m * m;
            mu[t][i] = m;
            rs[t][i] = rsqrtf(var + LN_EPS);
        }
#pragma unroll
    for (int t = 0; t < 2; ++t)
#pragma unroll
        for (int nt = 0; nt < 4; ++nt) {
            const int cc = wc * 64 + nt * 16 + ml;
            const float g = gamma[cc], be = beta[cc];
#pragma unroll
            for (int i = 0; i < 4; ++i) {
                const int node = nb + wr * 32 + t * 16 + kg * 4 + i;
                if (node < NNODES)
                    out[(size_t)node * DIM + cc] = (acc[t][nt][i] - mu[t][i]) * rs[t][i] * g + be;
            }
        }
}

extern "C" void kernel_launch(void* const* d_in, const int* in_sizes, int n_in,
                              void* d_out, int out_size, void* d_ws, size_t ws_size,
                              hipStream_t stream) {
    const float* x    = (const float*)d_in[0];
    const int*   eidx = (const int*)  d_in[1];
    const float* Wm   = (const float*)d_in[2];
    const float* bm   = (const float*)d_in[3];
    const float* Wu   = (const float*)d_in[4];
    const float* bu   = (const float*)d_in[5];
    const float* gam  = (const float*)d_in[6];
    const float* bet  = (const float*)d_in[7];
    float* out = (float*)d_out;

    char* ws = (char*)d_ws;
    ushort* xb     = (ushort*)(ws);                    //  5,120,000 B
    ushort* Ub     = (ushort*)(ws +  5120000);         //  5,120,000 B
    float*  Vf     = (float*) (ws + 10240000);         // 10,240,000 B
    ushort* aggb   = (ushort*)(ws + 20480000);         //  5,120,000 B
    ushort* Wcat   = (ushort*)(ws + 25600000);         //    262,144 B
    ushort* Wua    = (ushort*)(ws + 25862144);         //    262,144 B
    int*    cnt    = (int*)   (ws + 26124288);         //     40,960 B
    ushort* srow   = (ushort*)(ws + 26165248);         //  1,920,000 B (end ~28.1 MB)

    prep_all<<<3524, 256, 0, stream>>>(x, Wm, Wu, xb, Wcat, Wua, (int4*)cnt);
    scatter_uv<<<945, 256, 0, stream>>>(eidx, cnt, srow, xb, Wcat, bm, Ub, Vf);
    edge_combine<<<1250, 256, 0, stream>>>(Ub, Vf, srow, cnt, aggb);
    node_ln<<<157, 512, 0, stream>>>(xb, aggb, Wua, bu, gam, bet, out);
}

// Round 19
// 80.834 us; speedup vs baseline: 1.0789x; 1.0318x over previous
//
#include <hip/hip_runtime.h>
#include <hip/hip_bf16.h>
#include <stdint.h>

#define NNODES 10000
#define NEDGES 320000
#define DIM    256
#define KTOT   512
#define LN_EPS 1e-5f
#define BCAP   96     // per-node bucket capacity (max degree; P(exceed) ~ 1e-20)

typedef __attribute__((ext_vector_type(4))) float f32x4;
typedef __attribute__((ext_vector_type(8))) short bf16x8;

__device__ __forceinline__ ushort f2bf(float f) {
    union { float f; uint32_t u; } v; v.f = f;
    uint32_t r = v.u + 0x7fffu + ((v.u >> 16) & 1u);   // RNE
    return (ushort)(r >> 16);
}
__device__ __forceinline__ float bf2f(ushort u) {
    union { float f; uint32_t u; } v; v.u = ((uint32_t)u) << 16;
    return v.f;
}

// ---- K1: prep — cast x->bf16, zero cnt, fragment-arrange both W matrices ----
__global__ __launch_bounds__(256)
void prep_all(const float* __restrict__ x, const float* __restrict__ Wm,
              const float* __restrict__ Wu, ushort* __restrict__ xb,
              ushort* __restrict__ Wcat, ushort* __restrict__ Wua,
              int4* __restrict__ cntz) {
    int tid = blockIdx.x * 256 + threadIdx.x;          // 3524*256 = 902144
    if (tid < 2560) cntz[tid] = (int4){0, 0, 0, 0};    // 10240 ints >= NNODES
    if (tid < 640000) {                                // x cast, one float4 each
        float4 v = reinterpret_cast<const float4*>(x)[tid];
        ushort4 o;
        o.x = f2bf(v.x); o.y = f2bf(v.y); o.z = f2bf(v.z); o.w = f2bf(v.w);
        reinterpret_cast<ushort4*>(xb)[tid] = o;
    } else {
        int t = tid - 640000;                          // < 262144
        if (t < 131072) {
            int kk  = t >> 14;
            int rem = t & 16383;
            int g   = rem >> 9;
            int kg  = (rem >> 7) & 3;
            int ml  = (rem >> 3) & 15;
            int j   = rem & 7;
            int k = kk * 32 + kg * 8 + j;
            int n = g * 16 + ml;
            float v = (n < 256) ? Wm[k * DIM + n] : Wm[(k + 256) * DIM + (n - 256)];
            Wcat[t] = f2bf(v);
        } else {
            int rem = t - 131072;
            int kk  = rem >> 13;
            int nt  = (rem >> 9) & 15;
            int kg  = (rem >> 7) & 3;
            int ml  = (rem >> 3) & 15;
            int j   = rem & 7;
            int k = kk * 32 + kg * 8 + j;
            int n = nt * 16 + ml;
            Wua[rem] = f2bf(Wu[k * DIM + n]);
        }
    }
}

// ---- K2: ILP bucket scatter (blocks [0,320)) ∥ U|V GEMM (blocks [320,945)) ----
__global__ __launch_bounds__(256)
void scatter_uv(const int* __restrict__ eidx, int* __restrict__ cnt,
                ushort* __restrict__ srow, const ushort* __restrict__ xb,
                const ushort* __restrict__ Wcat, const float* __restrict__ bmsg,
                ushort* __restrict__ Ub, float* __restrict__ Vf) {
    if (blockIdx.x < 320) {
        const int t = blockIdx.x * 256 + threadIdx.x;  // 0..81919
        int d[4], r[4];
#pragma unroll
        for (int j = 0; j < 3; ++j) {                  // e < 245760 always valid
            int e = t + j * 81920;
            d[j] = eidx[NEDGES + e];
            r[j] = eidx[e];
        }
        const bool ok3 = t < (NEDGES - 3 * 81920);     // 74240
        if (ok3) { d[3] = eidx[NEDGES + t + 245760]; r[3] = eidx[t + 245760]; }
        int p[4];
#pragma unroll
        for (int j = 0; j < 3; ++j) p[j] = atomicAdd(&cnt[d[j]], 1);
        if (ok3) p[3] = atomicAdd(&cnt[d[3]], 1);
#pragma unroll
        for (int j = 0; j < 3; ++j)
            if (p[j] < BCAP) srow[d[j] * BCAP + p[j]] = (ushort)r[j];
        if (ok3 && p[3] < BCAP) srow[d[3] * BCAP + p[3]] = (ushort)r[3];
        return;
    }
    // U = x @ W_msg[:256] (bf16), V = x @ W_msg[256:] + b (fp32).
    // 625 blocks x 256 thr; block = 16 nodes x 512 cols; wave wq owns 128 cols.
    const int wq   = threadIdx.x >> 6;
    const int lane = threadIdx.x & 63;
    const int ml = lane & 15, kg = lane >> 4;
    const int nb = (blockIdx.x - 320) * 16;
    const uint arow = (uint)(nb + ml) * DIM;

    f32x4 acc[8];
#pragma unroll
    for (int nt = 0; nt < 8; ++nt) acc[nt] = (f32x4){0.f, 0.f, 0.f, 0.f};

#pragma unroll
    for (int kk = 0; kk < 8; ++kk) {
        bf16x8 a = *reinterpret_cast<const bf16x8*>(xb + arow + kk * 32 + kg * 8);
#pragma unroll
        for (int nt = 0; nt < 8; ++nt) {
            bf16x8 b = *reinterpret_cast<const bf16x8*>(Wcat + kk * 16384 + (wq * 8 + nt) * 512 + lane * 8);
            acc[nt] = __builtin_amdgcn_mfma_f32_16x16x32_bf16(a, b, acc[nt], 0, 0, 0);
        }
    }

    if (wq < 2) {                                   // U half: bf16
#pragma unroll
        for (int nt = 0; nt < 8; ++nt) {
            const int col = wq * 128 + nt * 16 + ml;
#pragma unroll
            for (int i = 0; i < 4; ++i)
                Ub[(size_t)(nb + kg * 4 + i) * 256 + col] = f2bf(acc[nt][i]);
        }
    } else {                                        // V half: fp32, bias folded
#pragma unroll
        for (int nt = 0; nt < 8; ++nt) {
            const int col = (wq - 2) * 128 + nt * 16 + ml;
            const float bb = bmsg[col];
#pragma unroll
            for (int i = 0; i < 4; ++i)
                Vf[(size_t)(nb + kg * 4 + i) * 256 + col] = acc[nt][i] + bb;
        }
    }
}

// ---- K3: edge combine, XCD column-split: aggb[d] = bf16( sum relu(U[src]+V[d]) )
// Grid 2504 = 313 groups x 8 (block i -> XCD i%8, round-robin). XCDs 0-3 own
// cols [0,128), XCDs 4-7 own [128,256): per-XCD U working set = 2.5 MB < 4 MiB
// L2 -> random row-gather becomes L2-resident.
// Block = 8 nodes (4 waves x 2). Wave: 16 col-lanes x 8 cols (16B loads kept),
// 4 edge-quarters (el = lane>>4) with 4-deep ILP; combine via shfl_xor(16,32).
__global__ __launch_bounds__(256)
void edge_combine(const ushort* __restrict__ Ub, const float* __restrict__ Vf,
                  const ushort* __restrict__ srow, const int* __restrict__ cnt,
                  ushort* __restrict__ aggb) {
    const int x = blockIdx.x & 7;          // presumed XCD id (round-robin)
    const int g = blockIdx.x >> 3;         // 0..312
    const int h = x >> 2;                  // column half
    const int t = g * 4 + (x & 3);         // node tile within half
    if (t >= 1250) return;

    const int wave = threadIdx.x >> 6, lane = threadIdx.x & 63;
    const int nb = t * 8;
    const int el = lane >> 4;              // edge quarter 0..3
    const int cl = lane & 15;              // col lane
    const int c0 = h * 128 + cl * 8;       // 8 cols owned (16B)

#pragma unroll
    for (int nn = 0; nn < 2; ++nn) {
        const int d = nb + wave * 2 + nn;
        int deg = cnt[d]; deg = deg < BCAP ? deg : BCAP;
        const int beg = d * BCAP;
        const float4 va = *reinterpret_cast<const float4*>(&Vf[(size_t)d * 256 + c0]);
        const float4 vb = *reinterpret_cast<const float4*>(&Vf[(size_t)d * 256 + c0 + 4]);
        float s[8];
#pragma unroll
        for (int j = 0; j < 8; ++j) s[j] = 0.f;

#define ACC8(U) do { \
        s[0] += fmaxf(bf2f((ushort)(U)[0]) + va.x, 0.f); \
        s[1] += fmaxf(bf2f((ushort)(U)[1]) + va.y, 0.f); \
        s[2] += fmaxf(bf2f((ushort)(U)[2]) + va.z, 0.f); \
        s[3] += fmaxf(bf2f((ushort)(U)[3]) + va.w, 0.f); \
        s[4] += fmaxf(bf2f((ushort)(U)[4]) + vb.x, 0.f); \
        s[5] += fmaxf(bf2f((ushort)(U)[5]) + vb.y, 0.f); \
        s[6] += fmaxf(bf2f((ushort)(U)[6]) + vb.z, 0.f); \
        s[7] += fmaxf(bf2f((ushort)(U)[7]) + vb.w, 0.f); } while (0)

        int i = el;                        // quarter el: edges el, el+4, el+8, ...
        for (; i + 12 < deg; i += 16) {    // 4 rows in flight per quarter
            int r0 = srow[beg + i],      r1 = srow[beg + i + 4];
            int r2 = srow[beg + i + 8],  r3 = srow[beg + i + 12];
            bf16x8 u0 = *reinterpret_cast<const bf16x8*>(&Ub[(size_t)r0 * 256 + c0]);
            bf16x8 u1 = *reinterpret_cast<const bf16x8*>(&Ub[(size_t)r1 * 256 + c0]);
            bf16x8 u2 = *reinterpret_cast<const bf16x8*>(&Ub[(size_t)r2 * 256 + c0]);
            bf16x8 u3 = *reinterpret_cast<const bf16x8*>(&Ub[(size_t)r3 * 256 + c0]);
            ACC8(u0); ACC8(u1); ACC8(u2); ACC8(u3);
        }
        for (; i < deg; i += 4) {
            int r = srow[beg + i];
            bf16x8 u = *reinterpret_cast<const bf16x8*>(&Ub[(size_t)r * 256 + c0]);
            ACC8(u);
        }
#undef ACC8
#pragma unroll
        for (int j = 0; j < 8; ++j) {
            s[j] += __shfl_xor(s[j], 16);
            s[j] += __shfl_xor(s[j], 32);
        }
        if (el == 0) {
            union { bf16x8 v; ushort hh[8]; } o;
#pragma unroll
            for (int j = 0; j < 8; ++j) o.hh[j] = f2bf(s[j]);
            *reinterpret_cast<bf16x8*>(&aggb[(size_t)d * 256 + c0]) = o.v;
        }
    }
}

// ---- K4: node update GEMM + bias + relu + LayerNorm (64-node tiles) ----
// 157 blocks x 512 thr (8 waves = 2 wr x 4 wc): wave = 32 nodes x 64 cols.
__global__ __launch_bounds__(512)
void node_ln(const ushort* __restrict__ xb, const ushort* __restrict__ aggb,
             const ushort* __restrict__ Wua, const float* __restrict__ bupd,
             const float* __restrict__ gamma, const float* __restrict__ beta,
             float* __restrict__ out) {
    __shared__ float pS[64][4][2];      // [node_local][wc][sum,ssq]

    const int wave = threadIdx.x >> 6;
    const int lane = threadIdx.x & 63;
    const int ml = lane & 15, kg = lane >> 4;
    const int wr = wave >> 2, wc = wave & 3;
    const int nb = blockIdx.x * 64;

    uint arow[2];
#pragma unroll
    for (int t = 0; t < 2; ++t) {
        int n = nb + wr * 32 + t * 16 + ml;
        arow[t] = (uint)(n < NNODES ? n : NNODES - 1) * DIM;
    }

    f32x4 acc[2][4];
#pragma unroll
    for (int t = 0; t < 2; ++t)
#pragma unroll
        for (int nt = 0; nt < 4; ++nt) acc[t][nt] = (f32x4){0.f, 0.f, 0.f, 0.f};

#pragma unroll
    for (int kk = 0; kk < 8; ++kk) {                  // k in [0,256): A = xb
        bf16x8 a0 = *reinterpret_cast<const bf16x8*>(xb + arow[0] + kk * 32 + kg * 8);
        bf16x8 a1 = *reinterpret_cast<const bf16x8*>(xb + arow[1] + kk * 32 + kg * 8);
#pragma unroll
        for (int nt = 0; nt < 4; ++nt) {
            bf16x8 b = *reinterpret_cast<const bf16x8*>(Wua + kk * 8192 + (wc * 4 + nt) * 512 + lane * 8);
            acc[0][nt] = __builtin_amdgcn_mfma_f32_16x16x32_bf16(a0, b, acc[0][nt], 0, 0, 0);
            acc[1][nt] = __builtin_amdgcn_mfma_f32_16x16x32_bf16(a1, b, acc[1][nt], 0, 0, 0);
        }
    }
#pragma unroll
    for (int kk = 0; kk < 8; ++kk) {                  // k in [256,512): A = aggb
        bf16x8 a0 = *reinterpret_cast<const bf16x8*>(aggb + arow[0] + kk * 32 + kg * 8);
        bf16x8 a1 = *reinterpret_cast<const bf16x8*>(aggb + arow[1] + kk * 32 + kg * 8);
#pragma unroll
        for (int nt = 0; nt < 4; ++nt) {
            bf16x8 b = *reinterpret_cast<const bf16x8*>(Wua + 65536 + kk * 8192 + (wc * 4 + nt) * 512 + lane * 8);
            acc[0][nt] = __builtin_amdgcn_mfma_f32_16x16x32_bf16(a0, b, acc[0][nt], 0, 0, 0);
            acc[1][nt] = __builtin_amdgcn_mfma_f32_16x16x32_bf16(a1, b, acc[1][nt], 0, 0, 0);
        }
    }

    float sum[2][4], ssq[2][4];
#pragma unroll
    for (int t = 0; t < 2; ++t)
#pragma unroll
        for (int i = 0; i < 4; ++i) { sum[t][i] = 0.f; ssq[t][i] = 0.f; }
#pragma unroll
    for (int t = 0; t < 2; ++t)
#pragma unroll
        for (int nt = 0; nt < 4; ++nt) {
            const float bb = bupd[wc * 64 + nt * 16 + ml];
#pragma unroll
            for (int i = 0; i < 4; ++i) {
                float v = acc[t][nt][i] + bb;
                v = v > 0.f ? v : 0.f;
                acc[t][nt][i] = v;
                sum[t][i] += v;
                ssq[t][i] += v * v;
            }
        }
#pragma unroll
    for (int m = 1; m < 16; m <<= 1) {
#pragma unroll
        for (int t = 0; t < 2; ++t)
#pragma unroll
            for (int i = 0; i < 4; ++i) {
                sum[t][i] += __shfl_xor(sum[t][i], m);
                ssq[t][i] += __shfl_xor(ssq[t][i], m);
            }
    }
    if (ml == 0) {
#pragma unroll
        for (int t = 0; t < 2; ++t)
#pragma unroll
            for (int i = 0; i < 4; ++i) {
                int nl = wr * 32 + t * 16 + kg * 4 + i;
                pS[nl][wc][0] = sum[t][i];
                pS[nl][wc][1] = ssq[t][i];
            }
    }
    __syncthreads();

    float mu[2][4], rs[2][4];
#pragma unroll
    for (int t = 0; t < 2; ++t)
#pragma unroll
        for (int i = 0; i < 4; ++i) {
            int nl = wr * 32 + t * 16 + kg * 4 + i;
            float S = pS[nl][0][0] + pS[nl][1][0] + pS[nl][2][0] + pS[nl][3][0];
            float Q = pS[nl][0][1] + pS[nl][1][1] + pS[nl][2][1] + pS[nl][3][1];
            float m = S * (1.f / 256.f);
            float var = Q * (1.f / 256.f) - m * m;
            mu[t][i] = m;
            rs[t][i] = rsqrtf(var + LN_EPS);
        }
#pragma unroll
    for (int t = 0; t < 2; ++t)
#pragma unroll
        for (int nt = 0; nt < 4; ++nt) {
            const int cc = wc * 64 + nt * 16 + ml;
            const float g = gamma[cc], be = beta[cc];
#pragma unroll
            for (int i = 0; i < 4; ++i) {
                const int node = nb + wr * 32 + t * 16 + kg * 4 + i;
                if (node < NNODES)
                    out[(size_t)node * DIM + cc] = (acc[t][nt][i] - mu[t][i]) * rs[t][i] * g + be;
            }
        }
}

extern "C" void kernel_launch(void* const* d_in, const int* in_sizes, int n_in,
                              void* d_out, int out_size, void* d_ws, size_t ws_size,
                              hipStream_t stream) {
    const float* x    = (const float*)d_in[0];
    const int*   eidx = (const int*)  d_in[1];
    const float* Wm   = (const float*)d_in[2];
    const float* bm   = (const float*)d_in[3];
    const float* Wu   = (const float*)d_in[4];
    const float* bu   = (const float*)d_in[5];
    const float* gam  = (const float*)d_in[6];
    const float* bet  = (const float*)d_in[7];
    float* out = (float*)d_out;

    char* ws = (char*)d_ws;
    ushort* xb     = (ushort*)(ws);                    //  5,120,000 B
    ushort* Ub     = (ushort*)(ws +  5120000);         //  5,120,000 B
    float*  Vf     = (float*) (ws + 10240000);         // 10,240,000 B
    ushort* aggb   = (ushort*)(ws + 20480000);         //  5,120,000 B
    ushort* Wcat   = (ushort*)(ws + 25600000);         //    262,144 B
    ushort* Wua    = (ushort*)(ws + 25862144);         //    262,144 B
    int*    cnt    = (int*)   (ws + 26124288);         //     40,960 B
    ushort* srow   = (ushort*)(ws + 26165248);         //  1,920,000 B (end ~28.1 MB)

    prep_all<<<3524, 256, 0, stream>>>(x, Wm, Wu, xb, Wcat, Wua, (int4*)cnt);
    scatter_uv<<<945, 256, 0, stream>>>(eidx, cnt, srow, xb, Wcat, bm, Ub, Vf);
    edge_combine<<<2504, 256, 0, stream>>>(Ub, Vf, srow, cnt, aggb);
    node_ln<<<157, 512, 0, stream>>>(xb, aggb, Wua, bu, gam, bet, out);
}

// Round 22
// 80.409 us; speedup vs baseline: 1.0846x; 1.0053x over previous
//
#include <hip/hip_runtime.h>
#include <hip/hip_bf16.h>
#include <stdint.h>

#define NNODES 10000
#define NEDGES 320000
#define DIM    256
#define KTOT   512
#define LN_EPS 1e-5f
#define BCAP   96     // per-node bucket capacity (max degree; P(exceed) ~ 1e-20)

typedef __attribute__((ext_vector_type(4))) float f32x4;
typedef __attribute__((ext_vector_type(8))) short bf16x8;

__device__ __forceinline__ ushort f2bf(float f) {
    union { float f; uint32_t u; } v; v.f = f;
    uint32_t r = v.u + 0x7fffu + ((v.u >> 16) & 1u);   // RNE
    return (ushort)(r >> 16);
}
__device__ __forceinline__ float bf2f(ushort u) {
    union { float f; uint32_t u; } v; v.u = ((uint32_t)u) << 16;
    return v.f;
}

// ---- K1: prep — cast x->bf16, zero cnt, fragment-arrange both W matrices ----
__global__ __launch_bounds__(256)
void prep_all(const float* __restrict__ x, const float* __restrict__ Wm,
              const float* __restrict__ Wu, ushort* __restrict__ xb,
              ushort* __restrict__ Wcat, ushort* __restrict__ Wua,
              int4* __restrict__ cntz) {
    int tid = blockIdx.x * 256 + threadIdx.x;          // 3524*256 = 902144
    if (tid < 2560) cntz[tid] = (int4){0, 0, 0, 0};    // 10240 ints >= NNODES
    if (tid < 640000) {                                // x cast, one float4 each
        float4 v = reinterpret_cast<const float4*>(x)[tid];
        ushort4 o;
        o.x = f2bf(v.x); o.y = f2bf(v.y); o.z = f2bf(v.z); o.w = f2bf(v.w);
        reinterpret_cast<ushort4*>(xb)[tid] = o;
    } else {
        int t = tid - 640000;                          // < 262144
        if (t < 131072) {
            int kk  = t >> 14;
            int rem = t & 16383;
            int g   = rem >> 9;
            int kg  = (rem >> 7) & 3;
            int ml  = (rem >> 3) & 15;
            int j   = rem & 7;
            int k = kk * 32 + kg * 8 + j;
            int n = g * 16 + ml;
            float v = (n < 256) ? Wm[k * DIM + n] : Wm[(k + 256) * DIM + (n - 256)];
            Wcat[t] = f2bf(v);
        } else {
            int rem = t - 131072;
            int kk  = rem >> 13;
            int nt  = (rem >> 9) & 15;
            int kg  = (rem >> 7) & 3;
            int ml  = (rem >> 3) & 15;
            int j   = rem & 7;
            int k = kk * 32 + kg * 8 + j;
            int n = nt * 16 + ml;
            Wua[rem] = f2bf(Wu[k * DIM + n]);
        }
    }
}

// ---- K2: ILP bucket scatter (blocks [0,320)) ∥ U|V GEMM (blocks [320,945)) ----
__global__ __launch_bounds__(256)
void scatter_uv(const int* __restrict__ eidx, int* __restrict__ cnt,
                ushort* __restrict__ srow, const ushort* __restrict__ xb,
                const ushort* __restrict__ Wcat, const float* __restrict__ bmsg,
                ushort* __restrict__ Ub, float* __restrict__ Vf) {
    if (blockIdx.x < 320) {
        const int t = blockIdx.x * 256 + threadIdx.x;  // 0..81919
        int d[4], r[4];
#pragma unroll
        for (int j = 0; j < 3; ++j) {                  // e < 245760 always valid
            int e = t + j * 81920;
            d[j] = eidx[NEDGES + e];
            r[j] = eidx[e];
        }
        const bool ok3 = t < (NEDGES - 3 * 81920);     // 74240
        if (ok3) { d[3] = eidx[NEDGES + t + 245760]; r[3] = eidx[t + 245760]; }
        int p[4];
#pragma unroll
        for (int j = 0; j < 3; ++j) p[j] = atomicAdd(&cnt[d[j]], 1);
        if (ok3) p[3] = atomicAdd(&cnt[d[3]], 1);
#pragma unroll
        for (int j = 0; j < 3; ++j)
            if (p[j] < BCAP) srow[d[j] * BCAP + p[j]] = (ushort)r[j];
        if (ok3 && p[3] < BCAP) srow[d[3] * BCAP + p[3]] = (ushort)r[3];
        return;
    }
    // U = x @ W_msg[:256] (bf16), V = x @ W_msg[256:] + b (fp32).
    // 625 blocks x 256 thr; block = 16 nodes x 512 cols; wave wq owns 128 cols.
    const int wq   = threadIdx.x >> 6;
    const int lane = threadIdx.x & 63;
    const int ml = lane & 15, kg = lane >> 4;
    const int nb = (blockIdx.x - 320) * 16;
    const uint arow = (uint)(nb + ml) * DIM;

    f32x4 acc[8];
#pragma unroll
    for (int nt = 0; nt < 8; ++nt) acc[nt] = (f32x4){0.f, 0.f, 0.f, 0.f};

#pragma unroll
    for (int kk = 0; kk < 8; ++kk) {
        bf16x8 a = *reinterpret_cast<const bf16x8*>(xb + arow + kk * 32 + kg * 8);
#pragma unroll
        for (int nt = 0; nt < 8; ++nt) {
            bf16x8 b = *reinterpret_cast<const bf16x8*>(Wcat + kk * 16384 + (wq * 8 + nt) * 512 + lane * 8);
            acc[nt] = __builtin_amdgcn_mfma_f32_16x16x32_bf16(a, b, acc[nt], 0, 0, 0);
        }
    }

    if (wq < 2) {                                   // U half: bf16
#pragma unroll
        for (int nt = 0; nt < 8; ++nt) {
            const int col = wq * 128 + nt * 16 + ml;
#pragma unroll
            for (int i = 0; i < 4; ++i)
                Ub[(size_t)(nb + kg * 4 + i) * 256 + col] = f2bf(acc[nt][i]);
        }
    } else {                                        // V half: fp32, bias folded
#pragma unroll
        for (int nt = 0; nt < 8; ++nt) {
            const int col = (wq - 2) * 128 + nt * 16 + ml;
            const float bb = bmsg[col];
#pragma unroll
            for (int i = 0; i < 4; ++i)
                Vf[(size_t)(nb + kg * 4 + i) * 256 + col] = acc[nt][i] + bb;
        }
    }
}

// ---- K3: edge combine (standalone): aggb[d] = bf16( sum relu(U[src] + V[d]) )
// 1250 blocks x 256 thr (4 waves); wave reduces 2 nodes; lane owns 8 cols
// (16B loads); 32-lane halves split edges by parity, 4-deep ILP, one
// shfl_xor(32) combine, bf16x8 store.
__global__ __launch_bounds__(256)
void edge_combine(const ushort* __restrict__ Ub, const float* __restrict__ Vf,
                  const ushort* __restrict__ srow, const int* __restrict__ cnt,
                  ushort* __restrict__ aggb) {
    const int wave = threadIdx.x >> 6, lane = threadIdx.x & 63;
    const int nb = blockIdx.x * 8;
    const int el = lane >> 5;           // half id (edge-parity)
    const int cl = lane & 31;
    const int c0 = cl * 8;              // 8 cols owned

#pragma unroll
    for (int nn = 0; nn < 2; ++nn) {
        const int d = nb + wave * 2 + nn;
        int deg = cnt[d]; deg = deg < BCAP ? deg : BCAP;
        const int beg = d * BCAP;
        const float4 va = *reinterpret_cast<const float4*>(&Vf[(size_t)d * 256 + c0]);
        const float4 vb = *reinterpret_cast<const float4*>(&Vf[(size_t)d * 256 + c0 + 4]);
        float s[8];
#pragma unroll
        for (int j = 0; j < 8; ++j) s[j] = 0.f;

#define ACC8(U) do { \
        s[0] += fmaxf(bf2f((ushort)(U)[0]) + va.x, 0.f); \
        s[1] += fmaxf(bf2f((ushort)(U)[1]) + va.y, 0.f); \
        s[2] += fmaxf(bf2f((ushort)(U)[2]) + va.z, 0.f); \
        s[3] += fmaxf(bf2f((ushort)(U)[3]) + va.w, 0.f); \
        s[4] += fmaxf(bf2f((ushort)(U)[4]) + vb.x, 0.f); \
        s[5] += fmaxf(bf2f((ushort)(U)[5]) + vb.y, 0.f); \
        s[6] += fmaxf(bf2f((ushort)(U)[6]) + vb.z, 0.f); \
        s[7] += fmaxf(bf2f((ushort)(U)[7]) + vb.w, 0.f); } while (0)

        int i = el;
        for (; i + 6 < deg; i += 8) {    // 4 rows in flight per half
            int r0 = srow[beg + i],     r1 = srow[beg + i + 2];
            int r2 = srow[beg + i + 4], r3 = srow[beg + i + 6];
            bf16x8 u0 = *reinterpret_cast<const bf16x8*>(&Ub[(size_t)r0 * 256 + c0]);
            bf16x8 u1 = *reinterpret_cast<const bf16x8*>(&Ub[(size_t)r1 * 256 + c0]);
            bf16x8 u2 = *reinterpret_cast<const bf16x8*>(&Ub[(size_t)r2 * 256 + c0]);
            bf16x8 u3 = *reinterpret_cast<const bf16x8*>(&Ub[(size_t)r3 * 256 + c0]);
            ACC8(u0); ACC8(u1); ACC8(u2); ACC8(u3);
        }
        for (; i < deg; i += 2) {
            int r = srow[beg + i];
            bf16x8 u = *reinterpret_cast<const bf16x8*>(&Ub[(size_t)r * 256 + c0]);
            ACC8(u);
        }
#undef ACC8
#pragma unroll
        for (int j = 0; j < 8; ++j) s[j] += __shfl_xor(s[j], 32);
        if (el == 0) {
            union { bf16x8 v; ushort h[8]; } o;
#pragma unroll
            for (int j = 0; j < 8; ++j) o.h[j] = f2bf(s[j]);
            *reinterpret_cast<bf16x8*>(&aggb[(size_t)d * 256 + c0]) = o.v;
        }
    }
}

// ---- K4: node update GEMM + bias + relu + LayerNorm (64-node tiles) ----
// 157 blocks x 512 thr (8 waves = 2 wr x 4 wc): wave = 32 nodes x 64 cols.
__global__ __launch_bounds__(512)
void node_ln(const ushort* __restrict__ xb, const ushort* __restrict__ aggb,
             const ushort* __restrict__ Wua, const float* __restrict__ bupd,
             const float* __restrict__ gamma, const float* __restrict__ beta,
             float* __restrict__ out) {
    __shared__ float pS[64][4][2];      // [node_local][wc][sum,ssq]

    const int wave = threadIdx.x >> 6;
    const int lane = threadIdx.x & 63;
    const int ml = lane & 15, kg = lane >> 4;
    const int wr = wave >> 2, wc = wave & 3;
    const int nb = blockIdx.x * 64;

    uint arow[2];
#pragma unroll
    for (int t = 0; t < 2; ++t) {
        int n = nb + wr * 32 + t * 16 + ml;
        arow[t] = (uint)(n < NNODES ? n : NNODES - 1) * DIM;
    }

    f32x4 acc[2][4];
#pragma unroll
    for (int t = 0; t < 2; ++t)
#pragma unroll
        for (int nt = 0; nt < 4; ++nt) acc[t][nt] = (f32x4){0.f, 0.f, 0.f, 0.f};

#pragma unroll
    for (int kk = 0; kk < 8; ++kk) {                  // k in [0,256): A = xb
        bf16x8 a0 = *reinterpret_cast<const bf16x8*>(xb + arow[0] + kk * 32 + kg * 8);
        bf16x8 a1 = *reinterpret_cast<const bf16x8*>(xb + arow[1] + kk * 32 + kg * 8);
#pragma unroll
        for (int nt = 0; nt < 4; ++nt) {
            bf16x8 b = *reinterpret_cast<const bf16x8*>(Wua + kk * 8192 + (wc * 4 + nt) * 512 + lane * 8);
            acc[0][nt] = __builtin_amdgcn_mfma_f32_16x16x32_bf16(a0, b, acc[0][nt], 0, 0, 0);
            acc[1][nt] = __builtin_amdgcn_mfma_f32_16x16x32_bf16(a1, b, acc[1][nt], 0, 0, 0);
        }
    }
#pragma unroll
    for (int kk = 0; kk < 8; ++kk) {                  // k in [256,512): A = aggb
        bf16x8 a0 = *reinterpret_cast<const bf16x8*>(aggb + arow[0] + kk * 32 + kg * 8);
        bf16x8 a1 = *reinterpret_cast<const bf16x8*>(aggb + arow[1] + kk * 32 + kg * 8);
#pragma unroll
        for (int nt = 0; nt < 4; ++nt) {
            bf16x8 b = *reinterpret_cast<const bf16x8*>(Wua + 65536 + kk * 8192 + (wc * 4 + nt) * 512 + lane * 8);
            acc[0][nt] = __builtin_amdgcn_mfma_f32_16x16x32_bf16(a0, b, acc[0][nt], 0, 0, 0);
            acc[1][nt] = __builtin_amdgcn_mfma_f32_16x16x32_bf16(a1, b, acc[1][nt], 0, 0, 0);
        }
    }

    float sum[2][4], ssq[2][4];
#pragma unroll
    for (int t = 0; t < 2; ++t)
#pragma unroll
        for (int i = 0; i < 4; ++i) { sum[t][i] = 0.f; ssq[t][i] = 0.f; }
#pragma unroll
    for (int t = 0; t < 2; ++t)
#pragma unroll
        for (int nt = 0; nt < 4; ++nt) {
            const float bb = bupd[wc * 64 + nt * 16 + ml];
#pragma unroll
            for (int i = 0; i < 4; ++i) {
                float v = acc[t][nt][i] + bb;
                v = v > 0.f ? v : 0.f;
                acc[t][nt][i] = v;
                sum[t][i] += v;
                ssq[t][i] += v * v;
            }
        }
#pragma unroll
    for (int m = 1; m < 16; m <<= 1) {
#pragma unroll
        for (int t = 0; t < 2; ++t)
#pragma unroll
            for (int i = 0; i < 4; ++i) {
                sum[t][i] += __shfl_xor(sum[t][i], m);
                ssq[t][i] += __shfl_xor(ssq[t][i], m);
            }
    }
    if (ml == 0) {
#pragma unroll
        for (int t = 0; t < 2; ++t)
#pragma unroll
            for (int i = 0; i < 4; ++i) {
                int nl = wr * 32 + t * 16 + kg * 4 + i;
                pS[nl][wc][0] = sum[t][i];
                pS[nl][wc][1] = ssq[t][i];
            }
    }
    __syncthreads();

    float mu[2][4], rs[2][4];
#pragma unroll
    for (int t = 0; t < 2; ++t)
#pragma unroll
        for (int i = 0; i < 4; ++i) {
            int nl = wr * 32 + t * 16 + kg * 4 + i;
            float S = pS[nl][0][0] + pS[nl][1][0] + pS[nl][2][0] + pS[nl][3][0];
            float Q = pS[nl][0][1] + pS[nl][1][1] + pS[nl][2][1] + pS[nl][3][1];
            float m = S * (1.f / 256.f);
            float var = Q * (1.f / 256.f) - m * m;
            mu[t][i] = m;
            rs[t][i] = rsqrtf(var + LN_EPS);
        }
#pragma unroll
    for (int t = 0; t < 2; ++t)
#pragma unroll
        for (int nt = 0; nt < 4; ++nt) {
            const int cc = wc * 64 + nt * 16 + ml;
            const float g = gamma[cc], be = beta[cc];
#pragma unroll
            for (int i = 0; i < 4; ++i) {
                const int node = nb + wr * 32 + t * 16 + kg * 4 + i;
                if (node < NNODES)
                    out[(size_t)node * DIM + cc] = (acc[t][nt][i] - mu[t][i]) * rs[t][i] * g + be;
            }
        }
}

extern "C" void kernel_launch(void* const* d_in, const int* in_sizes, int n_in,
                              void* d_out, int out_size, void* d_ws, size_t ws_size,
                              hipStream_t stream) {
    const float* x    = (const float*)d_in[0];
    const int*   eidx = (const int*)  d_in[1];
    const float* Wm   = (const float*)d_in[2];
    const float* bm   = (const float*)d_in[3];
    const float* Wu   = (const float*)d_in[4];
    const float* bu   = (const float*)d_in[5];
    const float* gam  = (const float*)d_in[6];
    const float* bet  = (const float*)d_in[7];
    float* out = (float*)d_out;

    char* ws = (char*)d_ws;
    ushort* xb     = (ushort*)(ws);                    //  5,120,000 B
    ushort* Ub     = (ushort*)(ws +  5120000);         //  5,120,000 B
    float*  Vf     = (float*) (ws + 10240000);         // 10,240,000 B
    ushort* aggb   = (ushort*)(ws + 20480000);         //  5,120,000 B
    ushort* Wcat   = (ushort*)(ws + 25600000);         //    262,144 B
    ushort* Wua    = (ushort*)(ws + 25862144);         //    262,144 B
    int*    cnt    = (int*)   (ws + 26124288);         //     40,960 B
    ushort* srow   = (ushort*)(ws + 26165248);         //  1,920,000 B (end ~28.1 MB)

    prep_all<<<3524, 256, 0, stream>>>(x, Wm, Wu, xb, Wcat, Wua, (int4*)cnt);
    scatter_uv<<<945, 256, 0, stream>>>(eidx, cnt, srow, xb, Wcat, bm, Ub, Vf);
    edge_combine<<<1250, 256, 0, stream>>>(Ub, Vf, srow, cnt, aggb);
    node_ln<<<157, 512, 0, stream>>>(xb, aggb, Wua, bu, gam, bet, out);
}